// Round 1
// baseline (223.117 us; speedup 1.0000x reference)
//
#include <hip/hip_runtime.h>
#include <math.h>

// TopK router: logits = x @ W^T (fp32), top-2 per token + softmax over the 2.
// x: [nTok, D] fp32, W: [E=64, D] fp32.
// out: [probs (nTok*2 f32)] ++ [idx (nTok*2, written as f32 values)]

#define BM 64      // tokens per block
#define BN 64      // experts (all)
#define BK 64      // k-chunk
#define TM 4
#define TN 4
#define THREADS 256
#define LDT (BM + 4)   // 68: keeps 16B alignment for float4 reads, breaks bank pattern

__global__ __launch_bounds__(THREADS)
void topk_router_kernel(const float* __restrict__ x,
                        const float* __restrict__ W,
                        float* __restrict__ out_probs,
                        float* __restrict__ out_idx,
                        int D) {
  __shared__ float As[BK][LDT];      // As[k][m]  (x tile, transposed)
  __shared__ float Bs[BK][LDT];      // Bs[k][e]  (W tile, transposed)
  __shared__ float Sl[BM][BN + 1];   // logits tile

  const int tid = threadIdx.x;
  const int tx  = tid & 15;   // expert-tile index (0..15)
  const int ty  = tid >> 4;   // token-tile index  (0..15)
  const int m0  = blockIdx.x * BM;

  const int lr = tid >> 4;    // staging row    (0..15)
  const int lc = tid & 15;    // staging f4 col (0..15)

  float acc[TM][TN];
#pragma unroll
  for (int i = 0; i < TM; ++i)
#pragma unroll
    for (int j = 0; j < TN; ++j) acc[i][j] = 0.f;

  const float* xBase = x + (size_t)m0 * D;

  for (int k0 = 0; k0 < D; k0 += BK) {
    // stage x tile -> As[k][m] (transposed). Coalesced float4 global reads.
#pragma unroll
    for (int p = 0; p < BM; p += 16) {
      const float4 v = *reinterpret_cast<const float4*>(
          xBase + (size_t)(p + lr) * D + (k0 + lc * 4));
      As[lc * 4 + 0][p + lr] = v.x;
      As[lc * 4 + 1][p + lr] = v.y;
      As[lc * 4 + 2][p + lr] = v.z;
      As[lc * 4 + 3][p + lr] = v.w;
    }
    // stage W tile -> Bs[k][e] (transposed)
#pragma unroll
    for (int p = 0; p < BN; p += 16) {
      const float4 v = *reinterpret_cast<const float4*>(
          W + (size_t)(p + lr) * D + (k0 + lc * 4));
      Bs[lc * 4 + 0][p + lr] = v.x;
      Bs[lc * 4 + 1][p + lr] = v.y;
      Bs[lc * 4 + 2][p + lr] = v.z;
      Bs[lc * 4 + 3][p + lr] = v.w;
    }
    __syncthreads();

#pragma unroll 8
    for (int kk = 0; kk < BK; ++kk) {
      const float4 a = *reinterpret_cast<const float4*>(&As[kk][ty * TM]);
      const float4 b = *reinterpret_cast<const float4*>(&Bs[kk][tx * TN]);
      const float av[TM] = {a.x, a.y, a.z, a.w};
      const float bv[TN] = {b.x, b.y, b.z, b.w};
#pragma unroll
      for (int i = 0; i < TM; ++i)
#pragma unroll
        for (int j = 0; j < TN; ++j)
          acc[i][j] = fmaf(av[i], bv[j], acc[i][j]);
    }
    __syncthreads();
  }

  // dump logits tile to LDS
#pragma unroll
  for (int i = 0; i < TM; ++i)
#pragma unroll
    for (int j = 0; j < TN; ++j)
      Sl[ty * TM + i][tx * TN + j] = acc[i][j];
  __syncthreads();

  // top-2 + softmax: one thread per token.
  // Strict '>' keeps the lowest index on ties (jax.lax.top_k semantics).
  if (tid < BM) {
    float b0 = -INFINITY, b1 = -INFINITY;
    int i0 = 0, i1 = 0;
    for (int e = 0; e < BN; ++e) {
      const float v = Sl[tid][e];
      if (v > b0) {
        b1 = b0; i1 = i0;
        b0 = v;  i0 = e;
      } else if (v > b1) {
        b1 = v; i1 = e;
      }
    }
    const float e1  = expf(b1 - b0);        // <= 1
    const float inv = 1.f / (1.f + e1);
    const int t = m0 + tid;
    out_probs[t * 2 + 0] = inv;             // softmax of [b0, b1]
    out_probs[t * 2 + 1] = e1 * inv;
    out_idx[t * 2 + 0] = (float)i0;
    out_idx[t * 2 + 1] = (float)i1;
  }
}

extern "C" void kernel_launch(void* const* d_in, const int* in_sizes, int n_in,
                              void* d_out, int out_size, void* d_ws, size_t ws_size,
                              hipStream_t stream) {
  const float* x = (const float*)d_in[0];
  const float* W = (const float*)d_in[1];

  const int E = 64;
  const int D = in_sizes[1] / E;            // 4096
  const int nTok = in_sizes[0] / D;         // 16384

  float* probs = (float*)d_out;                       // nTok*2 floats
  float* idxo  = (float*)d_out + (size_t)nTok * 2;    // nTok*2 "float" indices

  dim3 grid(nTok / BM), block(THREADS);
  hipLaunchKernelGGL(topk_router_kernel, grid, block, 0, stream,
                     x, W, probs, idxo, D);
}